// Round 6
// baseline (194.901 us; speedup 1.0000x reference)
//
#include <hip/hip_runtime.h>
#include <hip/hip_bf16.h>

#define D_MODEL 1024
#define NH 16
#define HD 64
#define S_LEN 2048
#define NB 2
#define M_TOT 4096
#define N3 3072

typedef __attribute__((ext_vector_type(8))) short bf16x8;
typedef __attribute__((ext_vector_type(4))) float f32x4;
typedef __attribute__((ext_vector_type(4))) unsigned short u16x4;

__device__ __forceinline__ unsigned short f2bf(float f) {
    unsigned int u = __float_as_uint(f);
    u += 0x7fffu + ((u >> 16) & 1u);
    return (unsigned short)(u >> 16);
}
__device__ __forceinline__ float bf2f(unsigned short s) {
    return __uint_as_float((unsigned int)s << 16);
}

#define GLOAD_LDS(gp, lp)                                                      \
    __builtin_amdgcn_global_load_lds(                                          \
        (const __attribute__((address_space(1))) void*)(gp),                   \
        (__attribute__((address_space(3))) void*)(lp), 16, 0, 0)

// ---------------------------------------------------------------- fused casts
__global__ __launch_bounds__(256) void cast_both(
    const float* __restrict__ x, const float* __restrict__ W,
    unsigned short* __restrict__ xb, unsigned short* __restrict__ Wb) {
    const int nx = M_TOT * D_MODEL / 4;
    const int nw = N3 * D_MODEL / 4;
    int i = blockIdx.x * 256 + threadIdx.x;
    const float* src;
    unsigned short* dst;
    int j;
    if (i < nx) { src = x; dst = xb; j = i; }
    else { j = i - nx; if (j >= nw) return; src = W; dst = Wb; }
    float4 v = reinterpret_cast<const float4*>(src)[j];
    u16x4 o;
    o.x = f2bf(v.x); o.y = f2bf(v.y); o.z = f2bf(v.z); o.w = f2bf(v.w);
    reinterpret_cast<u16x4*>(dst)[j] = o;
}

// ---------------------------------------------------------------- QKV GEMM
// m97 structure; MFMA operands SWAPPED (mfma(B,A)) so output cols sit in
// registers -> packed 8B stores + float4 bias loads in the epilogue.
#define BM 128
#define BN 128
#define BK 64

__global__ __launch_bounds__(256) void qkv_gemm(
    const unsigned short* __restrict__ A, const unsigned short* __restrict__ B,
    const float* __restrict__ bias, unsigned short* __restrict__ Z) {
    __shared__ unsigned short As[BM * BK];
    __shared__ unsigned short Bs[BN * BK];

    const int t = threadIdx.x;
    const int lane = t & 63;
    const int wid = t >> 6;
    const int wr = wid >> 1, wc = wid & 1;
    const int bm = blockIdx.y, bn = blockIdx.x;
    const int lr = lane & 15;
    const int lg = lane >> 4;
    const int srow = lane >> 3;
    const int sslot = lane & 7;

    f32x4 acc[4][4] = {};

    for (int k0 = 0; k0 < 1024; k0 += BK) {
        __syncthreads();
#pragma unroll
        for (int p = 0; p < 4; ++p) {
            int rb = wid * 32 + p * 8;
            int row = rb + srow;
            int seg = sslot ^ (row & 7);
            GLOAD_LDS(&A[(size_t)(bm * BM + row) * 1024 + k0 + seg * 8],
                      &As[rb * BK]);
            GLOAD_LDS(&B[(size_t)(bn * BN + row) * 1024 + k0 + seg * 8],
                      &Bs[rb * BK]);
        }
        __syncthreads();
#pragma unroll
        for (int ks = 0; ks < 2; ++ks) {
            bf16x8 af[4], bfr[4];
#pragma unroll
            for (int m = 0; m < 4; ++m) {
                int row = wr * 64 + m * 16 + lr;
                int slot = (ks * 4 + lg) ^ (row & 7);
                af[m] = *reinterpret_cast<const bf16x8*>(&As[row * BK + slot * 8]);
            }
#pragma unroll
            for (int n = 0; n < 4; ++n) {
                int row = wc * 64 + n * 16 + lr;
                int slot = (ks * 4 + lg) ^ (row & 7);
                bfr[n] = *reinterpret_cast<const bf16x8*>(&Bs[row * BK + slot * 8]);
            }
            // swapped: first operand = B rows (-> reg axis = output col),
            // second = A rows (-> lane axis = output row)
#pragma unroll
            for (int m = 0; m < 4; ++m)
#pragma unroll
                for (int n = 0; n < 4; ++n)
                    acc[m][n] = __builtin_amdgcn_mfma_f32_16x16x32_bf16(
                        bfr[n], af[m], acc[m][n], 0, 0, 0);
        }
    }
    // epilogue: D map (swapped): row = lane&15 (A), col = n*16 + lg*4 + i (B)
#pragma unroll
    for (int m = 0; m < 4; ++m) {
        int row = bm * BM + wr * 64 + m * 16 + lr;
#pragma unroll
        for (int n = 0; n < 4; ++n) {
            int colb = bn * BN + wc * 64 + n * 16 + lg * 4;
            float4 bv = *reinterpret_cast<const float4*>(&bias[colb]);
            u16x4 pk;
            pk.x = f2bf(acc[m][n][0] + bv.x);
            pk.y = f2bf(acc[m][n][1] + bv.y);
            pk.z = f2bf(acc[m][n][2] + bv.z);
            pk.w = f2bf(acc[m][n][3] + bv.w);
            *reinterpret_cast<u16x4*>(&Z[(size_t)row * N3 + colb]) = pk;
        }
    }
}

// ---------------------------------------------------------------- V transpose
__global__ __launch_bounds__(256) void transpose_v(
    const unsigned short* __restrict__ Z, unsigned short* __restrict__ Vt) {
    __shared__ unsigned short tile[64][72];
    int bid = blockIdx.x;
    int nh = bid >> 5;
    int cb = bid & 31;
    int n = nh >> 4, h = nh & 15;
    int t = threadIdx.x;
#pragma unroll
    for (int p = 0; p < 4; ++p) {
        int idx = p * 256 + t;
        int r = idx >> 4;
        int cg = idx & 15;
        u16x4 v = *reinterpret_cast<const u16x4*>(
            &Z[(size_t)(n * S_LEN + cb * 64 + r) * N3 + 2 * D_MODEL + h * HD + cg * 4]);
        *reinterpret_cast<u16x4*>(&tile[r][cg * 4]) = v;
    }
    __syncthreads();
#pragma unroll
    for (int p = 0; p < 4; ++p) {
        int idx = p * 256 + t;
        int d = idx >> 4;
        int cg = idx & 15;
        u16x4 o;
        o.x = tile[cg * 4 + 0][d];
        o.y = tile[cg * 4 + 1][d];
        o.z = tile[cg * 4 + 2][d];
        o.w = tile[cg * 4 + 3][d];
        *reinterpret_cast<u16x4*>(
            &Vt[((size_t)nh * 64 + d) * S_LEN + cb * 64 + cg * 4]) = o;
    }
}

// ---------------------------------------------------------------- flash attention
// Swapped QK^T (lane = one q-row) + swapped PV (q stays on lane axis ->
// in-lane rescale & divide, float4 out stores).  K double-buffered in LDS;
// V read directly from L2 (head-pinned; no staging).  LDS = 25.6 KB ->
// up to 5 blocks/CU.
__global__ __launch_bounds__(256) void attn(
    const unsigned short* __restrict__ Z, const unsigned short* __restrict__ Vt,
    float* __restrict__ Out) {
    const int ilin = blockIdx.y * 32 + blockIdx.x;
    const int head32 = (ilin & 7) * 4 + ((ilin >> 3) & 3);   // 4 heads per XCD
    const int qb = 31 - (ilin >> 5);                          // heavy-first
    const int n = head32 >> 4, h = head32 & 15;

    __shared__ unsigned short Kt[2][64 * 64];                // 16 KB
    __shared__ unsigned short p_lds[4][16][72];              // 9.2 KB

    const int t = threadIdx.x;
    const int lane = t & 63, w = t >> 6;
    const int lr = lane & 15, lg = lane >> 4;
    const int srow = lane >> 3, sslot = lane & 7;

    const float SCL = 0.03125f * 1.44269504f;   // 1/sqrt(1024) * log2(e)

    // Q fragment (B-operand of swapped QK: lane&15 = q), pre-scaled by SCL
    const size_t zrowQ = (size_t)(n * S_LEN + qb * 64 + w * 16 + lr) * N3 + D_MODEL + h * HD;
    bf16x8 qf[2];
#pragma unroll
    for (int f = 0; f < 2; ++f) {
        bf16x8 raw = *reinterpret_cast<const bf16x8*>(&Z[zrowQ + f * 32 + lg * 8]);
        bf16x8 sc;
#pragma unroll
        for (int j = 0; j < 8; ++j)
            sc[j] = (short)f2bf(bf2f((unsigned short)raw[j]) * SCL);
        qf[f] = sc;
    }

    auto STAGE = [&](int buf, int kb) {
#pragma unroll
        for (int p = 0; p < 2; ++p) {
            int rb = w * 16 + p * 8;
            int row = rb + srow;
            int seg = sslot ^ (row & 7);
            GLOAD_LDS(&Z[(size_t)(n * S_LEN + kb * 64 + row) * N3 + h * HD + seg * 8],
                      &Kt[buf][rb * 64]);
        }
    };

    f32x4 o[4] = {};
    float mrun = -1e30f, lrun = 0.f;   // per-lane: q-row = lane&15

    STAGE(0, 0);
    int cur = 0;
    for (int kb = 0; kb <= qb; ++kb) {
        __syncthreads();
        if (kb < qb) STAGE(cur ^ 1, kb + 1);
        const unsigned short* Kc = &Kt[cur][0];

        // hoisted V fragments (global, L2-hit; consumed after softmax)
        bf16x8 vf[2][4];
#pragma unroll
        for (int ks = 0; ks < 2; ++ks)
#pragma unroll
            for (int cfd = 0; cfd < 4; ++cfd)
                vf[ks][cfd] = *reinterpret_cast<const bf16x8*>(
                    &Vt[((size_t)head32 * 64 + cfd * 16 + lr) * S_LEN +
                        kb * 64 + ks * 32 + lg * 8]);

        // ---- S^T = K Q^T : lane holds s[cf][i] = S[key=cf*16+lg*4+i][q=lr]
        f32x4 s[4];
        __builtin_amdgcn_s_setprio(1);
#pragma unroll
        for (int cf = 0; cf < 4; ++cf) {
            int row = cf * 16 + lr;
            bf16x8 kf0 = *reinterpret_cast<const bf16x8*>(
                &Kc[row * 64 + ((lg) ^ (row & 7)) * 8]);
            bf16x8 kf1 = *reinterpret_cast<const bf16x8*>(
                &Kc[row * 64 + ((lg + 4) ^ (row & 7)) * 8]);
            f32x4 a = {};
            a = __builtin_amdgcn_mfma_f32_16x16x32_bf16(kf0, qf[0], a, 0, 0, 0);
            a = __builtin_amdgcn_mfma_f32_16x16x32_bf16(kf1, qf[1], a, 0, 0, 0);
            s[cf] = a;
        }
        __builtin_amdgcn_s_setprio(0);

        // ---- causal mask (diag tile only)
        if (kb == qb) {
            const int qloc = w * 16 + lr;
#pragma unroll
            for (int cf = 0; cf < 4; ++cf) {
                int kbase = cf * 16 + lg * 4;
#pragma unroll
                for (int i = 0; i < 4; ++i)
                    if (kbase + i > qloc) s[cf][i] = -1e30f;
            }
        }

        // ---- in-lane row max + 2-shfl reduce
        float pm;
        {
            f32x4 m4 = s[0];
#pragma unroll
            for (int cf = 1; cf < 4; ++cf) {
                m4[0] = fmaxf(m4[0], s[cf][0]); m4[1] = fmaxf(m4[1], s[cf][1]);
                m4[2] = fmaxf(m4[2], s[cf][2]); m4[3] = fmaxf(m4[3], s[cf][3]);
            }
            pm = fmaxf(fmaxf(m4[0], m4[1]), fmaxf(m4[2], m4[3]));
            pm = fmaxf(pm, __shfl_xor(pm, 16));
            pm = fmaxf(pm, __shfl_xor(pm, 32));
        }
        // ---- defer-max rescale (in-lane: o's q axis == lane axis)
        if (!__all(pm - mrun <= 8.0f)) {
            float mn = fmaxf(mrun, pm);
            float corr = exp2f(mrun - mn);
            mrun = mn;
            lrun *= corr;
#pragma unroll
            for (int cfd = 0; cfd < 4; ++cfd)
#pragma unroll
                for (int i = 0; i < 4; ++i) o[cfd][i] *= corr;
        }
        // ---- P = exp2(s - m); sum; pack pairs -> per-wave LDS
        float sum = 0.f;
#pragma unroll
        for (int cf = 0; cf < 4; ++cf) {
#pragma unroll
            for (int i = 0; i < 4; ++i) {
                float p = exp2f(s[cf][i] - mrun);
                s[cf][i] = p;
                sum += p;
            }
            unsigned int lo01 = (unsigned int)f2bf(s[cf][0]) |
                                ((unsigned int)f2bf(s[cf][1]) << 16);
            unsigned int lo23 = (unsigned int)f2bf(s[cf][2]) |
                                ((unsigned int)f2bf(s[cf][3]) << 16);
            *reinterpret_cast<unsigned int*>(&p_lds[w][lr][cf * 16 + lg * 4]) = lo01;
            *reinterpret_cast<unsigned int*>(&p_lds[w][lr][cf * 16 + lg * 4 + 2]) = lo23;
        }
        sum += __shfl_xor(sum, 16);
        sum += __shfl_xor(sum, 32);
        lrun += sum;

        // ---- O += P * V  (swapped: first op = V -> d on reg axis, q on lane)
        __builtin_amdgcn_s_setprio(1);
#pragma unroll
        for (int ks = 0; ks < 2; ++ks) {
            bf16x8 pf = *reinterpret_cast<const bf16x8*>(&p_lds[w][lr][ks * 32 + lg * 8]);
#pragma unroll
            for (int cfd = 0; cfd < 4; ++cfd) {
                o[cfd] = __builtin_amdgcn_mfma_f32_16x16x32_bf16(
                    vf[ks][cfd], pf, o[cfd], 0, 0, 0);
            }
        }
        __builtin_amdgcn_s_setprio(0);
        cur ^= 1;
    }
    // ---- epilogue: q on lane axis -> in-lane divide, float4 stores
    {
        float inv = 1.0f / lrun;
        int q = qb * 64 + w * 16 + lr;
#pragma unroll
        for (int cfd = 0; cfd < 4; ++cfd) {
            int dbase = h * HD + cfd * 16 + lg * 4;
            float4 ov;
            ov.x = o[cfd][0] * inv;
            ov.y = o[cfd][1] * inv;
            ov.z = o[cfd][2] * inv;
            ov.w = o[cfd][3] * inv;
            *reinterpret_cast<float4*>(
                &Out[(size_t)(n * S_LEN + q) * D_MODEL + dbase]) = ov;
        }
    }
}

// ----------------------------------------------------------------
extern "C" void kernel_launch(void* const* d_in, const int* in_sizes, int n_in,
                              void* d_out, int out_size, void* d_ws, size_t ws_size,
                              hipStream_t stream) {
    const float* x = (const float*)d_in[0];
    const float* W = (const float*)d_in[1];
    const float* b = (const float*)d_in[2];
    float* out = (float*)d_out;

    char* ws = (char*)d_ws;
    unsigned short* xb = (unsigned short*)ws;                                  // 8 MB
    unsigned short* Wb = (unsigned short*)(ws + (size_t)8 * 1024 * 1024);      // 6 MB
    unsigned short* Z  = (unsigned short*)(ws + (size_t)14 * 1024 * 1024);     // 24 MB
    unsigned short* Vt = (unsigned short*)(ws + (size_t)38 * 1024 * 1024);     // 8 MB

    cast_both<<<7168, 256, 0, stream>>>(x, W, xb, Wb);
    qkv_gemm<<<dim3(N3 / BN, M_TOT / BM), 256, 0, stream>>>(xb, Wb, b, Z);
    transpose_v<<<1024, 256, 0, stream>>>(Z, Vt);
    attn<<<dim3(32, 32), 256, 0, stream>>>(Z, Vt, out);
}

// Round 7
// 169.021 us; speedup vs baseline: 1.1531x; 1.1531x over previous
//
#include <hip/hip_runtime.h>
#include <hip/hip_bf16.h>

#define D_MODEL 1024
#define NH 16
#define HD 64
#define S_LEN 2048
#define NB 2
#define M_TOT 4096
#define N3 3072

typedef __attribute__((ext_vector_type(8))) short bf16x8;
typedef __attribute__((ext_vector_type(4))) float f32x4;
typedef __attribute__((ext_vector_type(4))) unsigned short u16x4;

__device__ __forceinline__ unsigned short f2bf(float f) {
    unsigned int u = __float_as_uint(f);
    u += 0x7fffu + ((u >> 16) & 1u);
    return (unsigned short)(u >> 16);
}
__device__ __forceinline__ float bf2f(unsigned short s) {
    return __uint_as_float((unsigned int)s << 16);
}

#define GLOAD_LDS(gp, lp)                                                      \
    __builtin_amdgcn_global_load_lds(                                          \
        (const __attribute__((address_space(1))) void*)(gp),                   \
        (__attribute__((address_space(3))) void*)(lp), 16, 0, 0)

// ---------------------------------------------------------------- fused casts
__global__ __launch_bounds__(256) void cast_both(
    const float* __restrict__ x, const float* __restrict__ W,
    unsigned short* __restrict__ xb, unsigned short* __restrict__ Wb) {
    const int nx = M_TOT * D_MODEL / 4;
    const int nw = N3 * D_MODEL / 4;
    int i = blockIdx.x * 256 + threadIdx.x;
    const float* src;
    unsigned short* dst;
    int j;
    if (i < nx) { src = x; dst = xb; j = i; }
    else { j = i - nx; if (j >= nw) return; src = W; dst = Wb; }
    float4 v = reinterpret_cast<const float4*>(src)[j];
    u16x4 o;
    o.x = f2bf(v.x); o.y = f2bf(v.y); o.z = f2bf(v.z); o.w = f2bf(v.w);
    reinterpret_cast<u16x4*>(dst)[j] = o;
}

// ---------------------------------------------------------------- QKV GEMM
// m97 structure; swapped mfma(B,A): output cols in regs -> packed 8B stores.
#define BM 128
#define BN 128
#define BK 64

__global__ __launch_bounds__(256) void qkv_gemm(
    const unsigned short* __restrict__ A, const unsigned short* __restrict__ B,
    const float* __restrict__ bias, unsigned short* __restrict__ Z) {
    __shared__ unsigned short As[BM * BK];
    __shared__ unsigned short Bs[BN * BK];

    const int t = threadIdx.x;
    const int lane = t & 63;
    const int wid = t >> 6;
    const int wr = wid >> 1, wc = wid & 1;
    const int bm = blockIdx.y, bn = blockIdx.x;
    const int lr = lane & 15;
    const int lg = lane >> 4;
    const int srow = lane >> 3;
    const int sslot = lane & 7;

    f32x4 acc[4][4] = {};

    for (int k0 = 0; k0 < 1024; k0 += BK) {
        __syncthreads();
#pragma unroll
        for (int p = 0; p < 4; ++p) {
            int rb = wid * 32 + p * 8;
            int row = rb + srow;
            int seg = sslot ^ (row & 7);
            GLOAD_LDS(&A[(size_t)(bm * BM + row) * 1024 + k0 + seg * 8],
                      &As[rb * BK]);
            GLOAD_LDS(&B[(size_t)(bn * BN + row) * 1024 + k0 + seg * 8],
                      &Bs[rb * BK]);
        }
        __syncthreads();
#pragma unroll
        for (int ks = 0; ks < 2; ++ks) {
            bf16x8 af[4], bfr[4];
#pragma unroll
            for (int m = 0; m < 4; ++m) {
                int row = wr * 64 + m * 16 + lr;
                int slot = (ks * 4 + lg) ^ (row & 7);
                af[m] = *reinterpret_cast<const bf16x8*>(&As[row * BK + slot * 8]);
            }
#pragma unroll
            for (int n = 0; n < 4; ++n) {
                int row = wc * 64 + n * 16 + lr;
                int slot = (ks * 4 + lg) ^ (row & 7);
                bfr[n] = *reinterpret_cast<const bf16x8*>(&Bs[row * BK + slot * 8]);
            }
#pragma unroll
            for (int m = 0; m < 4; ++m)
#pragma unroll
                for (int n = 0; n < 4; ++n)
                    acc[m][n] = __builtin_amdgcn_mfma_f32_16x16x32_bf16(
                        bfr[n], af[m], acc[m][n], 0, 0, 0);
        }
    }
    // D map (swapped): row = lane&15 (A axis), col = n*16 + lg*4 + i (B axis)
#pragma unroll
    for (int m = 0; m < 4; ++m) {
        int row = bm * BM + wr * 64 + m * 16 + lr;
#pragma unroll
        for (int n = 0; n < 4; ++n) {
            int colb = bn * BN + wc * 64 + n * 16 + lg * 4;
            float4 bv = *reinterpret_cast<const float4*>(&bias[colb]);
            u16x4 pk;
            pk.x = f2bf(acc[m][n][0] + bv.x);
            pk.y = f2bf(acc[m][n][1] + bv.y);
            pk.z = f2bf(acc[m][n][2] + bv.z);
            pk.w = f2bf(acc[m][n][3] + bv.w);
            *reinterpret_cast<u16x4*>(&Z[(size_t)row * N3 + colb]) = pk;
        }
    }
}

// ---------------------------------------------------------------- V transpose
__global__ __launch_bounds__(256) void transpose_v(
    const unsigned short* __restrict__ Z, unsigned short* __restrict__ Vt) {
    __shared__ unsigned short tile[64][72];
    int bid = blockIdx.x;
    int nh = bid >> 5;
    int cb = bid & 31;
    int n = nh >> 4, h = nh & 15;
    int t = threadIdx.x;
#pragma unroll
    for (int p = 0; p < 4; ++p) {
        int idx = p * 256 + t;
        int r = idx >> 4;
        int cg = idx & 15;
        u16x4 v = *reinterpret_cast<const u16x4*>(
            &Z[(size_t)(n * S_LEN + cb * 64 + r) * N3 + 2 * D_MODEL + h * HD + cg * 4]);
        *reinterpret_cast<u16x4*>(&tile[r][cg * 4]) = v;
    }
    __syncthreads();
#pragma unroll
    for (int p = 0; p < 4; ++p) {
        int idx = p * 256 + t;
        int d = idx >> 4;
        int cg = idx & 15;
        u16x4 o;
        o.x = tile[cg * 4 + 0][d];
        o.y = tile[cg * 4 + 1][d];
        o.z = tile[cg * 4 + 2][d];
        o.w = tile[cg * 4 + 3][d];
        *reinterpret_cast<u16x4*>(
            &Vt[((size_t)nh * 64 + d) * S_LEN + cb * 64 + cg * 4]) = o;
    }
}

// ---------------------------------------------------------------- flash attention
// Round-5 staging (K AND V double-buffered LDS via gload_lds) + swapped PV
// (q on lane axis -> in-lane rescale/divide) + unpadded swizzled P tile
// (LDS = 40960 B exactly -> 4 blocks/CU) + v_perm P packing.
__global__ __launch_bounds__(256, 4) void attn(
    const unsigned short* __restrict__ Z, const unsigned short* __restrict__ Vt,
    float* __restrict__ Out) {
    const int ilin = blockIdx.y * 32 + blockIdx.x;
    const int head32 = (ilin & 7) * 4 + ((ilin >> 3) & 3);   // 4 heads per XCD
    const int qb = 31 - (ilin >> 5);                          // heavy-first
    const int n = head32 >> 4, h = head32 & 15;

    __shared__ unsigned short Kt[2][64 * 64];      // 16 KB
    __shared__ unsigned short Vs[2][64 * 64];      // 16 KB
    __shared__ unsigned short p_lds[4][16 * 64];   // 8 KB, XOR-swizzled slots

    const int t = threadIdx.x;
    const int lane = t & 63, w = t >> 6;
    const int lr = lane & 15, lg = lane >> 4;
    const int r7 = lr & 7;
    const int srow = lane >> 3, sslot = lane & 7;

    const float SCL = 0.03125f * 1.44269504f;   // 1/sqrt(1024) * log2(e)

    // Q fragment (B-operand of swapped QK: lane&15 = q), pre-scaled by SCL
    const size_t zrowQ = (size_t)(n * S_LEN + qb * 64 + w * 16 + lr) * N3 + D_MODEL + h * HD;
    bf16x8 qf[2];
#pragma unroll
    for (int f = 0; f < 2; ++f) {
        bf16x8 raw = *reinterpret_cast<const bf16x8*>(&Z[zrowQ + f * 32 + lg * 8]);
        bf16x8 sc;
#pragma unroll
        for (int j = 0; j < 8; ++j)
            sc[j] = (short)f2bf(bf2f((unsigned short)raw[j]) * SCL);
        qf[f] = sc;
    }

    auto STAGE = [&](int buf, int kb) {
#pragma unroll
        for (int p = 0; p < 2; ++p) {
            int rb = w * 16 + p * 8;
            int row = rb + srow;
            int seg = sslot ^ (row & 7);
            GLOAD_LDS(&Z[(size_t)(n * S_LEN + kb * 64 + row) * N3 + h * HD + seg * 8],
                      &Kt[buf][rb * 64]);
            GLOAD_LDS(&Vt[((size_t)head32 * 64 + row) * S_LEN + kb * 64 + seg * 8],
                      &Vs[buf][rb * 64]);
        }
    };

    f32x4 o[4] = {};
    float mrun = -1e30f, lrun = 0.f;   // per-lane: q-row = lane&15
    unsigned short* pw = &p_lds[w][0];

    STAGE(0, 0);
    int cur = 0;
    for (int kb = 0; kb <= qb; ++kb) {
        __syncthreads();
        if (kb < qb) STAGE(cur ^ 1, kb + 1);
        const unsigned short* Kc = &Kt[cur][0];
        const unsigned short* Vc = &Vs[cur][0];

        // ---- S^T = K Q^T : lane holds s[cf][i] = S[key=cf*16+lg*4+i][q=lr]
        f32x4 s[4];
        __builtin_amdgcn_s_setprio(1);
#pragma unroll
        for (int cf = 0; cf < 4; ++cf) {
            int row = cf * 16 + lr;           // row&7 == lr&7
            bf16x8 kf0 = *reinterpret_cast<const bf16x8*>(
                &Kc[row * 64 + (lg ^ r7) * 8]);
            bf16x8 kf1 = *reinterpret_cast<const bf16x8*>(
                &Kc[row * 64 + ((lg + 4) ^ r7) * 8]);
            f32x4 a = {};
            a = __builtin_amdgcn_mfma_f32_16x16x32_bf16(kf0, qf[0], a, 0, 0, 0);
            a = __builtin_amdgcn_mfma_f32_16x16x32_bf16(kf1, qf[1], a, 0, 0, 0);
            s[cf] = a;
        }
        __builtin_amdgcn_s_setprio(0);

        // ---- causal mask (diag tile only)
        if (kb == qb) {
            const int qloc = w * 16 + lr;
#pragma unroll
            for (int cf = 0; cf < 4; ++cf) {
                int kbase = cf * 16 + lg * 4;
#pragma unroll
                for (int i = 0; i < 4; ++i)
                    if (kbase + i > qloc) s[cf][i] = -1e30f;
            }
        }

        // ---- in-lane row max + 2-shfl reduce
        float pm;
        {
            f32x4 m4 = s[0];
#pragma unroll
            for (int cf = 1; cf < 4; ++cf) {
                m4[0] = fmaxf(m4[0], s[cf][0]); m4[1] = fmaxf(m4[1], s[cf][1]);
                m4[2] = fmaxf(m4[2], s[cf][2]); m4[3] = fmaxf(m4[3], s[cf][3]);
            }
            pm = fmaxf(fmaxf(m4[0], m4[1]), fmaxf(m4[2], m4[3]));
            pm = fmaxf(pm, __shfl_xor(pm, 16));
            pm = fmaxf(pm, __shfl_xor(pm, 32));
        }
        // ---- defer-max rescale (in-lane: o's q axis == lane axis)
        if (!__all(pm - mrun <= 8.0f)) {
            float mn = fmaxf(mrun, pm);
            float corr = exp2f(mrun - mn);
            mrun = mn;
            lrun *= corr;
#pragma unroll
            for (int cfd = 0; cfd < 4; ++cfd)
#pragma unroll
                for (int i = 0; i < 4; ++i) o[cfd][i] *= corr;
        }
        // ---- P = exp2(s - m); sum; v_perm truncate-pack -> swizzled LDS
        float sum = 0.f;
#pragma unroll
        for (int cf = 0; cf < 4; ++cf) {
#pragma unroll
            for (int i = 0; i < 4; ++i) {
                float p = exp2f(s[cf][i] - mrun);
                s[cf][i] = p;
                sum += p;
            }
            // pack hi16(s0..s3) -> 2 dwords via v_perm (truncation)
            unsigned int lo01 = __builtin_amdgcn_perm(
                __float_as_uint(s[cf][1]), __float_as_uint(s[cf][0]), 0x07060302u);
            unsigned int lo23 = __builtin_amdgcn_perm(
                __float_as_uint(s[cf][3]), __float_as_uint(s[cf][2]), 0x07060302u);
            unsigned long long pk = (unsigned long long)lo01 |
                                    ((unsigned long long)lo23 << 32);
            int slot16 = (2 * cf + (lg >> 1)) ^ r7;
            *reinterpret_cast<unsigned long long*>(
                &pw[lr * 64 + slot16 * 8 + (lg & 1) * 4]) = pk;
        }
        sum += __shfl_xor(sum, 16);
        sum += __shfl_xor(sum, 32);
        lrun += sum;

        // ---- O += V * P  (swapped: d on reg axis, q on lane axis)
        __builtin_amdgcn_s_setprio(1);
#pragma unroll
        for (int ks = 0; ks < 2; ++ks) {
            bf16x8 pf = *reinterpret_cast<const bf16x8*>(
                &pw[lr * 64 + ((ks * 4 + lg) ^ r7) * 8]);
#pragma unroll
            for (int cfd = 0; cfd < 4; ++cfd) {
                int vrow = cfd * 16 + lr;     // vrow&7 == lr&7
                bf16x8 vf = *reinterpret_cast<const bf16x8*>(
                    &Vc[vrow * 64 + ((ks * 4 + lg) ^ r7) * 8]);
                o[cfd] = __builtin_amdgcn_mfma_f32_16x16x32_bf16(
                    vf, pf, o[cfd], 0, 0, 0);
            }
        }
        __builtin_amdgcn_s_setprio(0);
        cur ^= 1;
    }
    // ---- epilogue: in-lane divide, float4 stores
    {
        float inv = 1.0f / lrun;
        int q = qb * 64 + w * 16 + lr;
#pragma unroll
        for (int cfd = 0; cfd < 4; ++cfd) {
            int dbase = h * HD + cfd * 16 + lg * 4;
            float4 ov;
            ov.x = o[cfd][0] * inv;
            ov.y = o[cfd][1] * inv;
            ov.z = o[cfd][2] * inv;
            ov.w = o[cfd][3] * inv;
            *reinterpret_cast<float4*>(
                &Out[(size_t)(n * S_LEN + q) * D_MODEL + dbase]) = ov;
        }
    }
}

// ----------------------------------------------------------------
extern "C" void kernel_launch(void* const* d_in, const int* in_sizes, int n_in,
                              void* d_out, int out_size, void* d_ws, size_t ws_size,
                              hipStream_t stream) {
    const float* x = (const float*)d_in[0];
    const float* W = (const float*)d_in[1];
    const float* b = (const float*)d_in[2];
    float* out = (float*)d_out;

    char* ws = (char*)d_ws;
    unsigned short* xb = (unsigned short*)ws;                                  // 8 MB
    unsigned short* Wb = (unsigned short*)(ws + (size_t)8 * 1024 * 1024);      // 6 MB
    unsigned short* Z  = (unsigned short*)(ws + (size_t)14 * 1024 * 1024);     // 24 MB
    unsigned short* Vt = (unsigned short*)(ws + (size_t)38 * 1024 * 1024);     // 8 MB

    cast_both<<<7168, 256, 0, stream>>>(x, W, xb, Wb);
    qkv_gemm<<<dim3(N3 / BN, M_TOT / BM), 256, 0, stream>>>(xb, Wb, b, Z);
    transpose_v<<<1024, 256, 0, stream>>>(Z, Vt);
    attn<<<dim3(32, 32), 256, 0, stream>>>(Z, Vt, out);
}

// Round 8
// 153.189 us; speedup vs baseline: 1.2723x; 1.1034x over previous
//
#include <hip/hip_runtime.h>
#include <hip/hip_bf16.h>

#define D_MODEL 1024
#define NH 16
#define HD 64
#define S_LEN 2048
#define NB 2
#define M_TOT 4096
#define N3 3072

typedef __attribute__((ext_vector_type(8))) short bf16x8;
typedef __attribute__((ext_vector_type(4))) float f32x4;
typedef __attribute__((ext_vector_type(4))) unsigned short u16x4;

__device__ __forceinline__ unsigned short f2bf(float f) {
    unsigned int u = __float_as_uint(f);
    u += 0x7fffu + ((u >> 16) & 1u);
    return (unsigned short)(u >> 16);
}
__device__ __forceinline__ float bf2f(unsigned short s) {
    return __uint_as_float((unsigned int)s << 16);
}

#define GLOAD_LDS(gp, lp)                                                      \
    __builtin_amdgcn_global_load_lds(                                          \
        (const __attribute__((address_space(1))) void*)(gp),                   \
        (__attribute__((address_space(3))) void*)(lp), 16, 0, 0)

// ---------------------------------------------------------------- fused casts
__global__ __launch_bounds__(256) void cast_both(
    const float* __restrict__ x, const float* __restrict__ W,
    unsigned short* __restrict__ xb, unsigned short* __restrict__ Wb) {
    const int nx = M_TOT * D_MODEL / 4;
    const int nw = N3 * D_MODEL / 4;
    int i = blockIdx.x * 256 + threadIdx.x;
    const float* src;
    unsigned short* dst;
    int j;
    if (i < nx) { src = x; dst = xb; j = i; }
    else { j = i - nx; if (j >= nw) return; src = W; dst = Wb; }
    float4 v = reinterpret_cast<const float4*>(src)[j];
    u16x4 o;
    o.x = f2bf(v.x); o.y = f2bf(v.y); o.z = f2bf(v.z); o.w = f2bf(v.w);
    reinterpret_cast<u16x4*>(dst)[j] = o;
}

// ---------------------------------------------------------------- QKV GEMM
// m97 structure; swapped mfma(B,A); bijective XCD swizzle (768 % 8 == 0).
#define BM 128
#define BN 128
#define BK 64

__global__ __launch_bounds__(256) void qkv_gemm(
    const unsigned short* __restrict__ A, const unsigned short* __restrict__ B,
    const float* __restrict__ bias, unsigned short* __restrict__ Z) {
    __shared__ unsigned short As[BM * BK];
    __shared__ unsigned short Bs[BN * BK];

    const int t = threadIdx.x;
    const int lane = t & 63;
    const int wid = t >> 6;
    const int wr = wid >> 1, wc = wid & 1;
    // XCD-aware swizzle: 768 workgroups, 8 XCDs, 96 per XCD (bijective)
    const int lin = blockIdx.y * 24 + blockIdx.x;
    const int swz = (lin & 7) * 96 + (lin >> 3);
    const int bm = swz / 24, bn = swz % 24;
    const int lr = lane & 15;
    const int lg = lane >> 4;
    const int srow = lane >> 3;
    const int sslot = lane & 7;

    f32x4 acc[4][4] = {};

    for (int k0 = 0; k0 < 1024; k0 += BK) {
        __syncthreads();
#pragma unroll
        for (int p = 0; p < 4; ++p) {
            int rb = wid * 32 + p * 8;
            int row = rb + srow;
            int seg = sslot ^ (row & 7);
            GLOAD_LDS(&A[(size_t)(bm * BM + row) * 1024 + k0 + seg * 8],
                      &As[rb * BK]);
            GLOAD_LDS(&B[(size_t)(bn * BN + row) * 1024 + k0 + seg * 8],
                      &Bs[rb * BK]);
        }
        __syncthreads();
#pragma unroll
        for (int ks = 0; ks < 2; ++ks) {
            bf16x8 af[4], bfr[4];
#pragma unroll
            for (int m = 0; m < 4; ++m) {
                int row = wr * 64 + m * 16 + lr;
                int slot = (ks * 4 + lg) ^ (row & 7);
                af[m] = *reinterpret_cast<const bf16x8*>(&As[row * BK + slot * 8]);
            }
#pragma unroll
            for (int n = 0; n < 4; ++n) {
                int row = wc * 64 + n * 16 + lr;
                int slot = (ks * 4 + lg) ^ (row & 7);
                bfr[n] = *reinterpret_cast<const bf16x8*>(&Bs[row * BK + slot * 8]);
            }
#pragma unroll
            for (int m = 0; m < 4; ++m)
#pragma unroll
                for (int n = 0; n < 4; ++n)
                    acc[m][n] = __builtin_amdgcn_mfma_f32_16x16x32_bf16(
                        bfr[n], af[m], acc[m][n], 0, 0, 0);
        }
    }
    // D map (swapped): row = lane&15 (A axis), col = n*16 + lg*4 + i (B axis)
#pragma unroll
    for (int m = 0; m < 4; ++m) {
        int row = bm * BM + wr * 64 + m * 16 + lr;
#pragma unroll
        for (int n = 0; n < 4; ++n) {
            int colb = bn * BN + wc * 64 + n * 16 + lg * 4;
            float4 bv = *reinterpret_cast<const float4*>(&bias[colb]);
            u16x4 pk;
            pk.x = f2bf(acc[m][n][0] + bv.x);
            pk.y = f2bf(acc[m][n][1] + bv.y);
            pk.z = f2bf(acc[m][n][2] + bv.z);
            pk.w = f2bf(acc[m][n][3] + bv.w);
            *reinterpret_cast<u16x4*>(&Z[(size_t)row * N3 + colb]) = pk;
        }
    }
}

// ---------------------------------------------------------------- V transpose
__global__ __launch_bounds__(256) void transpose_v(
    const unsigned short* __restrict__ Z, unsigned short* __restrict__ Vt) {
    __shared__ unsigned short tile[64][72];
    int bid = blockIdx.x;
    int nh = bid >> 5;
    int cb = bid & 31;
    int n = nh >> 4, h = nh & 15;
    int t = threadIdx.x;
#pragma unroll
    for (int p = 0; p < 4; ++p) {
        int idx = p * 256 + t;
        int r = idx >> 4;
        int cg = idx & 15;
        u16x4 v = *reinterpret_cast<const u16x4*>(
            &Z[(size_t)(n * S_LEN + cb * 64 + r) * N3 + 2 * D_MODEL + h * HD + cg * 4]);
        *reinterpret_cast<u16x4*>(&tile[r][cg * 4]) = v;
    }
    __syncthreads();
#pragma unroll
    for (int p = 0; p < 4; ++p) {
        int idx = p * 256 + t;
        int d = idx >> 4;
        int cg = idx & 15;
        u16x4 o;
        o.x = tile[cg * 4 + 0][d];
        o.y = tile[cg * 4 + 1][d];
        o.z = tile[cg * 4 + 2][d];
        o.w = tile[cg * 4 + 3][d];
        *reinterpret_cast<u16x4*>(
            &Vt[((size_t)nh * 64 + d) * S_LEN + cb * 64 + cg * 4]) = o;
    }
}

// ---------------------------------------------------------------- flash attention
// Shift-invariant softmax with NO running max: out = sum(exp2(s) v)/sum(exp2(s))
// exactly (constant shift cancels; s bounded ~100 -> exp2 cannot overflow f32,
// masked -1e30 -> exp2 = 0).  Row-sum computed on the MFMA pipe via a
// ones-operand mfma.  K,V double-buffered LDS; swapped QK & PV keep q on the
// lane axis throughout -> zero cross-lane ops in the whole kernel.
__global__ __launch_bounds__(256, 4) void attn(
    const unsigned short* __restrict__ Z, const unsigned short* __restrict__ Vt,
    float* __restrict__ Out) {
    const int ilin = blockIdx.y * 32 + blockIdx.x;
    const int head32 = (ilin & 7) * 4 + ((ilin >> 3) & 3);   // 4 heads per XCD
    const int qb = 31 - (ilin >> 5);                          // heavy-first
    const int n = head32 >> 4, h = head32 & 15;

    __shared__ unsigned short Kt[2][64 * 64];      // 16 KB
    __shared__ unsigned short Vs[2][64 * 64];      // 16 KB
    __shared__ unsigned short p_lds[4][16 * 64];   // 8 KB, XOR-swizzled slots

    const int t = threadIdx.x;
    const int lane = t & 63, w = t >> 6;
    const int lr = lane & 15, lg = lane >> 4;
    const int r7 = lr & 7;
    const int srow = lane >> 3, sslot = lane & 7;

    const float SCL = 0.03125f * 1.44269504f;   // 1/sqrt(1024) * log2(e)

    // Q fragment (B-operand of swapped QK: lane&15 = q), pre-scaled by SCL
    const size_t zrowQ = (size_t)(n * S_LEN + qb * 64 + w * 16 + lr) * N3 + D_MODEL + h * HD;
    bf16x8 qf[2];
#pragma unroll
    for (int f = 0; f < 2; ++f) {
        bf16x8 raw = *reinterpret_cast<const bf16x8*>(&Z[zrowQ + f * 32 + lg * 8]);
        bf16x8 sc;
#pragma unroll
        for (int j = 0; j < 8; ++j)
            sc[j] = (short)f2bf(bf2f((unsigned short)raw[j]) * SCL);
        qf[f] = sc;
    }
    bf16x8 ones;
#pragma unroll
    for (int j = 0; j < 8; ++j) ones[j] = (short)0x3F80;   // 1.0 bf16

    auto STAGE = [&](int buf, int kb) {
#pragma unroll
        for (int p = 0; p < 2; ++p) {
            int rb = w * 16 + p * 8;
            int row = rb + srow;
            int seg = sslot ^ (row & 7);
            GLOAD_LDS(&Z[(size_t)(n * S_LEN + kb * 64 + row) * N3 + h * HD + seg * 8],
                      &Kt[buf][rb * 64]);
            GLOAD_LDS(&Vt[((size_t)head32 * 64 + row) * S_LEN + kb * 64 + seg * 8],
                      &Vs[buf][rb * 64]);
        }
    };

    f32x4 o[4] = {};
    f32x4 osum = {};                       // all 4 components = running sum(P)
    unsigned short* pw = &p_lds[w][0];

    STAGE(0, 0);
    int cur = 0;
    for (int kb = 0; kb <= qb; ++kb) {
        __syncthreads();
        if (kb < qb) STAGE(cur ^ 1, kb + 1);
        const unsigned short* Kc = &Kt[cur][0];
        const unsigned short* Vc = &Vs[cur][0];

        // ---- S^T = K Q^T : lane holds s[cf][i] = S[key=cf*16+lg*4+i][q=lr]
        f32x4 s[4];
        __builtin_amdgcn_s_setprio(1);
#pragma unroll
        for (int cf = 0; cf < 4; ++cf) {
            int row = cf * 16 + lr;           // row&7 == lr&7
            bf16x8 kf0 = *reinterpret_cast<const bf16x8*>(
                &Kc[row * 64 + (lg ^ r7) * 8]);
            bf16x8 kf1 = *reinterpret_cast<const bf16x8*>(
                &Kc[row * 64 + ((lg + 4) ^ r7) * 8]);
            f32x4 a = {};
            a = __builtin_amdgcn_mfma_f32_16x16x32_bf16(kf0, qf[0], a, 0, 0, 0);
            a = __builtin_amdgcn_mfma_f32_16x16x32_bf16(kf1, qf[1], a, 0, 0, 0);
            s[cf] = a;
        }
        __builtin_amdgcn_s_setprio(0);

        // ---- causal mask (diag tile only)
        if (kb == qb) {
            const int qloc = w * 16 + lr;
#pragma unroll
            for (int cf = 0; cf < 4; ++cf) {
                int kbase = cf * 16 + lg * 4;
#pragma unroll
                for (int i = 0; i < 4; ++i)
                    if (kbase + i > qloc) s[cf][i] = -1e30f;
            }
        }

        // ---- P = exp2(s) (no max-sub: shift cancels in the final divide);
        //      v_perm truncate-pack -> swizzled per-wave LDS
#pragma unroll
        for (int cf = 0; cf < 4; ++cf) {
#pragma unroll
            for (int i = 0; i < 4; ++i) s[cf][i] = exp2f(s[cf][i]);
            unsigned int lo01 = __builtin_amdgcn_perm(
                __float_as_uint(s[cf][1]), __float_as_uint(s[cf][0]), 0x07060302u);
            unsigned int lo23 = __builtin_amdgcn_perm(
                __float_as_uint(s[cf][3]), __float_as_uint(s[cf][2]), 0x07060302u);
            unsigned long long pk = (unsigned long long)lo01 |
                                    ((unsigned long long)lo23 << 32);
            int slot16 = (2 * cf + (lg >> 1)) ^ r7;
            *reinterpret_cast<unsigned long long*>(
                &pw[lr * 64 + slot16 * 8 + (lg & 1) * 4]) = pk;
        }

        // ---- O += V * P ; row-sum on the MFMA pipe via ones-operand
        __builtin_amdgcn_s_setprio(1);
#pragma unroll
        for (int ks = 0; ks < 2; ++ks) {
            bf16x8 pf = *reinterpret_cast<const bf16x8*>(
                &pw[lr * 64 + ((ks * 4 + lg) ^ r7) * 8]);
            osum = __builtin_amdgcn_mfma_f32_16x16x32_bf16(ones, pf, osum, 0, 0, 0);
#pragma unroll
            for (int cfd = 0; cfd < 4; ++cfd) {
                int vrow = cfd * 16 + lr;     // vrow&7 == lr&7
                bf16x8 vf = *reinterpret_cast<const bf16x8*>(
                    &Vc[vrow * 64 + ((ks * 4 + lg) ^ r7) * 8]);
                o[cfd] = __builtin_amdgcn_mfma_f32_16x16x32_bf16(
                    vf, pf, o[cfd], 0, 0, 0);
            }
        }
        __builtin_amdgcn_s_setprio(0);
        cur ^= 1;
    }
    // ---- epilogue: in-lane divide, float4 stores
    {
        float inv = 1.0f / osum[0];
        int q = qb * 64 + w * 16 + lr;
#pragma unroll
        for (int cfd = 0; cfd < 4; ++cfd) {
            int dbase = h * HD + cfd * 16 + lg * 4;
            float4 ov;
            ov.x = o[cfd][0] * inv;
            ov.y = o[cfd][1] * inv;
            ov.z = o[cfd][2] * inv;
            ov.w = o[cfd][3] * inv;
            *reinterpret_cast<float4*>(
                &Out[(size_t)(n * S_LEN + q) * D_MODEL + dbase]) = ov;
        }
    }
}

// ----------------------------------------------------------------
extern "C" void kernel_launch(void* const* d_in, const int* in_sizes, int n_in,
                              void* d_out, int out_size, void* d_ws, size_t ws_size,
                              hipStream_t stream) {
    const float* x = (const float*)d_in[0];
    const float* W = (const float*)d_in[1];
    const float* b = (const float*)d_in[2];
    float* out = (float*)d_out;

    char* ws = (char*)d_ws;
    unsigned short* xb = (unsigned short*)ws;                                  // 8 MB
    unsigned short* Wb = (unsigned short*)(ws + (size_t)8 * 1024 * 1024);      // 6 MB
    unsigned short* Z  = (unsigned short*)(ws + (size_t)14 * 1024 * 1024);     // 24 MB
    unsigned short* Vt = (unsigned short*)(ws + (size_t)38 * 1024 * 1024);     // 8 MB

    cast_both<<<7168, 256, 0, stream>>>(x, W, xb, Wb);
    qkv_gemm<<<dim3(N3 / BN, M_TOT / BM), 256, 0, stream>>>(xb, Wb, b, Z);
    transpose_v<<<1024, 256, 0, stream>>>(Z, Vt);
    attn<<<dim3(32, 32), 256, 0, stream>>>(Z, Vt, out);
}